// Round 7
// baseline (226.517 us; speedup 1.0000x reference)
//
#include <hip/hip_runtime.h>
#include <math.h>

typedef __attribute__((ext_vector_type(8))) short bf16x8;
typedef __attribute__((ext_vector_type(4))) float f32x4;

__device__ __forceinline__ unsigned short f32_to_bf16_rne(float f) {
    unsigned int u = __float_as_uint(f);
    unsigned int r = (u + 0x7FFFu + ((u >> 16) & 1u)) >> 16;
    return (unsigned short)r;
}
__device__ __forceinline__ float bf16_to_f32(unsigned short h) {
    return __uint_as_float(((unsigned int)h) << 16);
}
__device__ __forceinline__ unsigned int pck(unsigned short a, unsigned short b) {
    return (unsigned int)a | ((unsigned int)b << 16);
}

// ---------------------------------------------------------------------------
// K0: k_prep — split all weights to bf16 hi/lo AND pack into MFMA-frag-chunk
// layouts.
//  Wfc  -> Bpkh/Bpkl  [24 steps][16 frags][64][8] shorts (classes padded 256)
//  Wl/Wm/Ws -> B2h/B2l [12 tiles][24 steps][4 frags][64][8] shorts
// frag layout: idx = k_octet*16 + col_lo, elem = k&7  (matches MFMA B lane map)
// ---------------------------------------------------------------------------
__global__ __launch_bounds__(256) void k_prep(
    const float* __restrict__ Wfc, const float* __restrict__ Wl,
    const float* __restrict__ Wm, const float* __restrict__ Ws,
    unsigned short* __restrict__ Bpkh, unsigned short* __restrict__ Bpkl,
    unsigned short* __restrict__ B2h, unsigned short* __restrict__ B2l)
{
    const int blk = blockIdx.x, tid = threadIdx.x;
    const float* src; int idx, rows, cbase; bool isfc;
    if (blk < 192)      { isfc = true;  idx = blk * 256 + tid;        src = Wfc; rows = 200; cbase = 0; }
    else if (blk < 336) { isfc = false; idx = (blk - 192) * 256 + tid; src = Wl;  rows = 192; cbase = 0; }
    else if (blk < 480) { isfc = false; idx = (blk - 336) * 256 + tid; src = Wm;  rows = 192; cbase = 192; }
    else                { isfc = false; idx = (blk - 480) * 256 + tid; src = Ws;  rows = 384; cbase = 384; }
    const int c = idx / 192;            // local row (class)
    const int kk = (idx % 192) * 4;     // k base (multiple of 4)
    unsigned short h[4] = {0, 0, 0, 0}, l[4] = {0, 0, 0, 0};
    if (c < rows) {
        const float4 w = *(const float4*)&src[(size_t)c * 768 + kk];
        const float wv[4] = {w.x, w.y, w.z, w.w};
#pragma unroll
        for (int j = 0; j < 4; ++j) {
            h[j] = f32_to_bf16_rne(wv[j]);
            l[j] = f32_to_bf16_rne(wv[j] - bf16_to_f32(h[j]));
        }
    }
    const int step = kk >> 5, oct = (kk & 31) >> 3, elem = kk & 7;
    const uint2 uh = make_uint2(pck(h[0], h[1]), pck(h[2], h[3]));
    const uint2 ul = make_uint2(pck(l[0], l[1]), pck(l[2], l[3]));
    if (isfc) {
        const size_t off = (size_t)((step * 16 + (c >> 4)) * 64 + oct * 16 + (c & 15)) * 8 + elem;
        *(uint2*)&Bpkh[off] = uh;
        *(uint2*)&Bpkl[off] = ul;
    } else {
        const int cg = cbase + c;
        const int tt = cg >> 6, cc = cg & 63;
        const size_t off = (size_t)(((tt * 24 + step) * 4 + (cc >> 4)) * 64 + oct * 16 + (cc & 15)) * 8 + elem;
        *(uint2*)&B2h[off] = uh;
        *(uint2*)&B2l[off] = ul;
    }
}

// ---------------------------------------------------------------------------
// K1: fused logits GEMM + softmax-denominator.  BM=64, BN=256 (all classes),
// BK=32, 24 steps. 4 waves, 1M x 4N (wave = 64 rows x 64 cols).
// Double-buffered LDS, issue-early/write-late prefetch, ONE barrier per step.
// Epilogue: in-register row max + sumexp -> maxprob (logits never hit HBM).
// ---------------------------------------------------------------------------
__global__ __launch_bounds__(256) void k_logits_fused(
    const float* __restrict__ x, const unsigned short* __restrict__ Bpkh,
    const unsigned short* __restrict__ Bpkl, const float* __restrict__ bfc,
    float* __restrict__ maxprob)
{
    __shared__ unsigned short AhS[2][4][64][8];    // 8 KB
    __shared__ unsigned short AlS[2][4][64][8];    // 8 KB
    __shared__ unsigned short BhS[2][16][64][8];   // 32 KB
    __shared__ unsigned short BlS[2][16][64][8];   // 32 KB
    __shared__ float sbias[256];
    __shared__ float red[4][64];
    __shared__ float red2[4][64];

    const int tid = threadIdx.x;
    const int lane = tid & 63;
    const int wid = tid >> 6;              // n-wave 0..3
    const int row0 = blockIdx.x * 64;

    sbias[tid] = (tid < 200) ? bfc[tid] : -1e30f;

    // A staging: row ar, k-octet ap (per wave)
    const int ar = tid & 63, ap = tid >> 6;
    const float* xb = x + (size_t)(row0 + ar) * 768 + ap * 8;
    // B staging: flat frag-chunk copy, 4 uint4 per thread per half
    const uint4* bhs = (const uint4*)Bpkh;
    const uint4* bls = (const uint4*)Bpkl;

    float ag[8];
    uint4 bgh[4], bgl[4];

    f32x4 acc[4][4];
    const f32x4 z = {0.f, 0.f, 0.f, 0.f};
#pragma unroll
    for (int mf = 0; mf < 4; ++mf)
#pragma unroll
        for (int q = 0; q < 4; ++q) acc[mf][q] = z;

    auto LOADAB = [&](int t) {
        const float4 v0 = *(const float4*)(xb + t * 32);
        const float4 v1 = *(const float4*)(xb + t * 32 + 4);
        ag[0] = v0.x; ag[1] = v0.y; ag[2] = v0.z; ag[3] = v0.w;
        ag[4] = v1.x; ag[5] = v1.y; ag[6] = v1.z; ag[7] = v1.w;
#pragma unroll
        for (int j = 0; j < 4; ++j) {
            bgh[j] = bhs[t * 1024 + j * 256 + tid];
            bgl[j] = bls[t * 1024 + j * 256 + tid];
        }
    };
    auto WRITEAB = [&](int buf) {
        unsigned short h[8], l[8];
#pragma unroll
        for (int j = 0; j < 8; ++j) {
            h[j] = f32_to_bf16_rne(ag[j]);
            l[j] = f32_to_bf16_rne(ag[j] - bf16_to_f32(h[j]));
        }
        *(uint4*)&AhS[buf][ar >> 4][ap * 16 + (ar & 15)][0] =
            make_uint4(pck(h[0], h[1]), pck(h[2], h[3]), pck(h[4], h[5]), pck(h[6], h[7]));
        *(uint4*)&AlS[buf][ar >> 4][ap * 16 + (ar & 15)][0] =
            make_uint4(pck(l[0], l[1]), pck(l[2], l[3]), pck(l[4], l[5]), pck(l[6], l[7]));
        uint4* bdh = (uint4*)&BhS[buf][0][0][0];
        uint4* bdl = (uint4*)&BlS[buf][0][0][0];
#pragma unroll
        for (int j = 0; j < 4; ++j) {
            bdh[j * 256 + tid] = bgh[j];
            bdl[j * 256 + tid] = bgl[j];
        }
    };

    LOADAB(0);
    WRITEAB(0);
    __syncthreads();

    for (int t = 0; t < 24; ++t) {
        const int cur = t & 1;
        if (t < 23) LOADAB(t + 1);     // overlaps MFMA phase below
        bf16x8 ah[4], al2[4];
#pragma unroll
        for (int mf = 0; mf < 4; ++mf) {
            ah[mf]  = *(const bf16x8*)&AhS[cur][mf][lane][0];
            al2[mf] = *(const bf16x8*)&AlS[cur][mf][lane][0];
        }
#pragma unroll
        for (int q = 0; q < 4; ++q) {
            const bf16x8 bh = *(const bf16x8*)&BhS[cur][wid * 4 + q][lane][0];
            const bf16x8 bl = *(const bf16x8*)&BlS[cur][wid * 4 + q][lane][0];
#pragma unroll
            for (int mf = 0; mf < 4; ++mf) {
                acc[mf][q] = __builtin_amdgcn_mfma_f32_16x16x32_bf16(al2[mf], bh, acc[mf][q], 0, 0, 0);
                acc[mf][q] = __builtin_amdgcn_mfma_f32_16x16x32_bf16(ah[mf], bl, acc[mf][q], 0, 0, 0);
                acc[mf][q] = __builtin_amdgcn_mfma_f32_16x16x32_bf16(ah[mf], bh, acc[mf][q], 0, 0, 0);
            }
        }
        if (t < 23) WRITEAB(cur ^ 1);  // consumes the loads issued above
        __syncthreads();
    }

    // ---- fused softmax denominator ----
    // element [mf][q][r] = logit[row = mf*16+(lane>>4)*4+r][col = wid*64+q*16+(lane&15)]
    float bv[4];
#pragma unroll
    for (int q = 0; q < 4; ++q) bv[q] = sbias[wid * 64 + q * 16 + (lane & 15)];

    float mrow[4][4];
#pragma unroll
    for (int mf = 0; mf < 4; ++mf)
#pragma unroll
        for (int r = 0; r < 4; ++r) {
            float mx = -1e30f;
#pragma unroll
            for (int q = 0; q < 4; ++q) mx = fmaxf(mx, acc[mf][q][r] + bv[q]);
#pragma unroll
            for (int s = 1; s < 16; s <<= 1) mx = fmaxf(mx, __shfl_xor(mx, s, 64));
            mrow[mf][r] = mx;
            if ((lane & 15) == 0) red[wid][mf * 16 + (lane >> 4) * 4 + r] = mx;
        }
    __syncthreads();
#pragma unroll
    for (int mf = 0; mf < 4; ++mf)
#pragma unroll
        for (int r = 0; r < 4; ++r) {
            const int row = mf * 16 + (lane >> 4) * 4 + r;
            const float m = fmaxf(fmaxf(red[0][row], red[1][row]),
                                  fmaxf(red[2][row], red[3][row]));
            float se = 0.f;
#pragma unroll
            for (int q = 0; q < 4; ++q) se += __expf(acc[mf][q][r] + bv[q] - m);
#pragma unroll
            for (int s = 1; s < 16; s <<= 1) se += __shfl_xor(se, s, 64);
            if ((lane & 15) == 0) red2[wid][row] = se;
            (void)mrow[mf][r];
        }
    __syncthreads();
    if (wid == 0 && (lane & 15) == 0) {
#pragma unroll
        for (int mf = 0; mf < 4; ++mf)
#pragma unroll
            for (int r = 0; r < 4; ++r) {
                const int row = mf * 16 + (lane >> 4) * 4 + r;
                maxprob[row0 + row] = 1.0f /
                    (red2[0][row] + red2[1][row] + red2[2][row] + red2[3][row]);
            }
    }
}

// ---------------------------------------------------------------------------
// K2: part_logits + argmax -> sel  (unchanged, correct)
// ---------------------------------------------------------------------------
__global__ void k_sel(const float* __restrict__ maxprob,
                      const float* __restrict__ mask, int* __restrict__ sel)
{
    __shared__ float mp[784];
    __shared__ float pl[81];
    const int b = blockIdx.x, tid = threadIdx.x;
    for (int i = tid; i < 784; i += blockDim.x) mp[i] = maxprob[b * 784 + i];
    __syncthreads();
    if (tid < 81) {
        const int pr = tid / 9, pc = tid % 9;
        float s = 0.f;
        for (int ki = 0; ki < 8; ++ki) {
            const int y = pr * 3 - 2 + ki;
            if (y < 0 || y >= 28) continue;
            for (int kj = 0; kj < 8; ++kj) {
                const int xx = pc * 3 - 2 + kj;
                if (xx < 0 || xx >= 28) continue;
                s += mp[y * 28 + xx];
            }
        }
        pl[tid] = mask[b * 81 + tid] * (s * (1.f / 64.f));
    }
    __syncthreads();
    if (tid == 0) {
        float best = pl[0]; int bi = 0;
        for (int i = 1; i < 81; ++i) if (pl[i] > best) { best = pl[i]; bi = i; }
        sel[b] = bi;
    }
}

__device__ __forceinline__ void rcoef8(int o, int n, int& f0, int& f1, float& w)
{
    float s = (o + 0.5f) * ((float)n * 0.125f) - 0.5f;
    s = fminf(fmaxf(s, 0.f), (float)(n - 1));
    f0 = (int)s;
    w = s - (float)f0;
    f1 = f0 + 1; if (f1 > n - 1) f1 = n - 1;
}

// ---------------------------------------------------------------------------
// K3: fused build + ff GEMM, pipelined. grid = 16 b x 12 n-tiles of 64.
// Gather goes to registers; bilinear via __shfl (corners live in lanes of the
// same wave); double-buffered frag LDS; ONE barrier per step; packed B.
// ---------------------------------------------------------------------------
__global__ __launch_bounds__(256) void k_ff(
    const float* __restrict__ x, const int* __restrict__ sel,
    const unsigned short* __restrict__ B2h, const unsigned short* __restrict__ B2l,
    const float* __restrict__ bl, const float* __restrict__ bm,
    const float* __restrict__ bs_, float* __restrict__ out)
{
    __shared__ unsigned short AhS[2][4][64][8];   // 8 KB
    __shared__ unsigned short AlS[2][4][64][8];   // 8 KB
    __shared__ unsigned short BhS[2][4][64][8];   // 8 KB
    __shared__ unsigned short BlS[2][4][64][8];   // 8 KB

    const int blk = blockIdx.x;
    const int b = blk / 12, t = blk % 12;
    const int n0 = t * 64;
    const int seg = (t < 3) ? 0 : ((t < 6) ? 1 : 2);
    const float* bias = (seg == 0) ? (bl + t * 64)
                      : (seg == 1) ? (bm + (t - 3) * 64)
                                   : (bs_ + (t - 6) * 64);
    const int s = sel[b];
    const int wy0 = (s / 9) * 3 - 2, wx0 = (s % 9) * 3 - 2;

    const int tid = threadIdx.x;
    const int lane = tid & 63;
    const int wid = tid >> 6, wmi = wid & 1, wn = wid >> 1;

    // gather: lane = window position (8x8), wave = k-octet
    const int gy = wy0 + (lane >> 3), gx = wx0 + (lane & 7);
    const bool inb = (gy >= 0 && gy < 28 && gx >= 0 && gx < 28);
    const float* xsrc = x + ((size_t)b * 784 + (inb ? (gy * 28 + gx) : 0)) * 768 + wid * 8;

    // bilinear corners for output row ai = lane
    int r00, r01, r10, r11; float fx = 0.f, fy = 0.f;
    if (seg == 0) { r00 = r01 = r10 = r11 = lane; }
    else {
        const int nn = (seg == 1) ? 6 : 4, off = (seg == 1) ? 1 : 2;
        int f0y, f1y, f0x, f1x;
        rcoef8(lane >> 3, nn, f0y, f1y, fy);
        rcoef8(lane & 7, nn, f0x, f1x, fx);
        r00 = (off + f0y) * 8 + off + f0x;
        r01 = (off + f0y) * 8 + off + f1x;
        r10 = (off + f1y) * 8 + off + f0x;
        r11 = (off + f1y) * 8 + off + f1x;
    }

    // B: packed per (tile, step): 256 uint4 per half
    const uint4* b2h = (const uint4*)B2h + (size_t)t * 24 * 256;
    const uint4* b2l = (const uint4*)B2l + (size_t)t * 24 * 256;

    float g[8];
    uint4 bh_r, bl_r;

    f32x4 acc[2][2];
    const f32x4 z = {0.f, 0.f, 0.f, 0.f};
#pragma unroll
    for (int mi = 0; mi < 2; ++mi)
#pragma unroll
        for (int q = 0; q < 2; ++q) acc[mi][q] = z;

    auto LOAD = [&](int st) {
        if (inb) {
            const float4 v0 = *(const float4*)(xsrc + st * 32);
            const float4 v1 = *(const float4*)(xsrc + st * 32 + 4);
            g[0] = v0.x; g[1] = v0.y; g[2] = v0.z; g[3] = v0.w;
            g[4] = v1.x; g[5] = v1.y; g[6] = v1.z; g[7] = v1.w;
        } else {
#pragma unroll
            for (int j = 0; j < 8; ++j) g[j] = 0.f;
        }
        bh_r = b2h[st * 256 + tid];
        bl_r = b2l[st * 256 + tid];
    };
    auto WRITE = [&](int buf) {
        unsigned short h[8], l[8];
#pragma unroll
        for (int j = 0; j < 8; ++j) {
            const float v00 = __shfl(g[j], r00, 64);
            const float v01 = __shfl(g[j], r01, 64);
            const float v10 = __shfl(g[j], r10, 64);
            const float v11 = __shfl(g[j], r11, 64);
            const float v0 = v00 + fx * (v01 - v00);
            const float v1 = v10 + fx * (v11 - v10);
            const float a = v0 + fy * (v1 - v0);
            h[j] = f32_to_bf16_rne(a);
            l[j] = f32_to_bf16_rne(a - bf16_to_f32(h[j]));
        }
        *(uint4*)&AhS[buf][lane >> 4][wid * 16 + (lane & 15)][0] =
            make_uint4(pck(h[0], h[1]), pck(h[2], h[3]), pck(h[4], h[5]), pck(h[6], h[7]));
        *(uint4*)&AlS[buf][lane >> 4][wid * 16 + (lane & 15)][0] =
            make_uint4(pck(l[0], l[1]), pck(l[2], l[3]), pck(l[4], l[5]), pck(l[6], l[7]));
        ((uint4*)&BhS[buf][0][0][0])[tid] = bh_r;
        ((uint4*)&BlS[buf][0][0][0])[tid] = bl_r;
    };

    LOAD(0);
    WRITE(0);
    __syncthreads();

    for (int st = 0; st < 24; ++st) {
        const int cur = st & 1;
        if (st < 23) LOAD(st + 1);
        bf16x8 ah[2], al2[2];
#pragma unroll
        for (int mi = 0; mi < 2; ++mi) {
            ah[mi]  = *(const bf16x8*)&AhS[cur][wmi * 2 + mi][lane][0];
            al2[mi] = *(const bf16x8*)&AlS[cur][wmi * 2 + mi][lane][0];
        }
#pragma unroll
        for (int q = 0; q < 2; ++q) {
            const bf16x8 bh = *(const bf16x8*)&BhS[cur][wn * 2 + q][lane][0];
            const bf16x8 bl2 = *(const bf16x8*)&BlS[cur][wn * 2 + q][lane][0];
#pragma unroll
            for (int mi = 0; mi < 2; ++mi) {
                acc[mi][q] = __builtin_amdgcn_mfma_f32_16x16x32_bf16(al2[mi], bh, acc[mi][q], 0, 0, 0);
                acc[mi][q] = __builtin_amdgcn_mfma_f32_16x16x32_bf16(ah[mi], bl2, acc[mi][q], 0, 0, 0);
                acc[mi][q] = __builtin_amdgcn_mfma_f32_16x16x32_bf16(ah[mi], bh, acc[mi][q], 0, 0, 0);
            }
        }
        if (st < 23) WRITE(cur ^ 1);
        __syncthreads();
    }

#pragma unroll
    for (int mi = 0; mi < 2; ++mi)
#pragma unroll
        for (int q = 0; q < 2; ++q)
#pragma unroll
            for (int r = 0; r < 4; ++r) {
                const int row = wmi * 32 + mi * 16 + (lane >> 4) * 4 + r;
                const int col = wn * 32 + q * 16 + (lane & 15);
                out[((size_t)b * 64 + row) * 768 + n0 + col] = acc[mi][q][r] + bias[col];
            }
}

// ---------------------------------------------------------------------------
// K4: image_part gather + 128->224 bilinear. Unchanged.
// ---------------------------------------------------------------------------
__global__ __launch_bounds__(256) void k_image(
    const float* __restrict__ img, const int* __restrict__ sel,
    float* __restrict__ out)
{
    const int idx = blockIdx.x * 256 + threadIdx.x;
    if (idx >= 16 * 3 * 224 * 224) return;
    const int ox = idx % 224;
    int t = idx / 224;
    const int oy = t % 224; t /= 224;
    const int c = t % 3;
    const int b = t / 3;
    const int s = sel[b];
    const int ry0 = (s / 9) * 48 - 32, cx0 = (s % 9) * 48 - 32;

    float sy = (oy + 0.5f) * (128.f / 224.f) - 0.5f;
    sy = fminf(fmaxf(sy, 0.f), 127.f);
    const int fy0 = (int)sy; const float wy = sy - (float)fy0;
    const int fy1 = (fy0 < 127) ? fy0 + 1 : 127;

    float sx = (ox + 0.5f) * (128.f / 224.f) - 0.5f;
    sx = fminf(fmaxf(sx, 0.f), 127.f);
    const int fx0 = (int)sx; const float wx = sx - (float)fx0;
    const int fx1 = (fx0 < 127) ? fx0 + 1 : 127;

    const float* ib = img + ((size_t)b * 3 + c) * 448 * 448;
    auto rd = [&](int py, int px) -> float {
        const int r = ry0 + py, cc = cx0 + px;
        return (r >= 0 && r < 448 && cc >= 0 && cc < 448) ? ib[r * 448 + cc] : 0.f;
    };
    const float g00 = rd(fy0, fx0), g01 = rd(fy0, fx1);
    const float g10 = rd(fy1, fx0), g11 = rd(fy1, fx1);
    const float v0 = g00 + wx * (g01 - g00);
    const float v1 = g10 + wx * (g11 - g10);
    out[idx] = v0 + wy * (v1 - v0);
}

// ---------------------------------------------------------------------------
extern "C" void kernel_launch(void* const* d_in, const int* in_sizes, int n_in,
                              void* d_out, int out_size, void* d_ws, size_t ws_size,
                              hipStream_t stream)
{
    const float* x    = (const float*)d_in[0];
    const float* mask = (const float*)d_in[1];
    const float* img  = (const float*)d_in[2];
    const float* Wfc  = (const float*)d_in[3];
    const float* bfc  = (const float*)d_in[4];
    const float* Wl   = (const float*)d_in[5];
    const float* bl   = (const float*)d_in[6];
    const float* Wm   = (const float*)d_in[7];
    const float* bm   = (const float*)d_in[8];
    const float* Ws   = (const float*)d_in[9];
    const float* bs   = (const float*)d_in[10];
    float* out = (float*)d_out;

    char* ws = (char*)d_ws;
    float* maxprob       = (float*)ws;                          // 50176 B
    int*   sel           = (int*)(ws + 51200);                  // 64 B
    unsigned short* Bpkh = (unsigned short*)(ws + 65536);       // 393216 B
    unsigned short* Bpkl = (unsigned short*)(ws + 458752);      // 393216 B
    unsigned short* B2h  = (unsigned short*)(ws + 851968);      // 1179648 B
    unsigned short* B2l  = (unsigned short*)(ws + 2031616);     // 1179648 B

    hipLaunchKernelGGL(k_prep,         dim3(768),  dim3(256), 0, stream,
                       Wfc, Wl, Wm, Ws, Bpkh, Bpkl, B2h, B2l);
    hipLaunchKernelGGL(k_logits_fused, dim3(196),  dim3(256), 0, stream,
                       x, Bpkh, Bpkl, bfc, maxprob);
    hipLaunchKernelGGL(k_sel,          dim3(16),   dim3(128), 0, stream,
                       maxprob, mask, sel);
    hipLaunchKernelGGL(k_ff,           dim3(192),  dim3(256), 0, stream,
                       x, sel, B2h, B2l, bl, bm, bs, out);
    hipLaunchKernelGGL(k_image,        dim3(9408), dim3(256), 0, stream,
                       img, sel, out + 786432);
}